// Round 1
// baseline (798.078 us; speedup 1.0000x reference)
//
#include <hip/hip_runtime.h>
#include <cstdint>
#include <cstddef>

// Problem constants
#define T_TOK 8192
#define HDIM  1024
#define FDIM  2048
#define NEXP  16
#define CAP   1280

typedef __bf16 bf16x8 __attribute__((ext_vector_type(8)));
typedef float  f32x4  __attribute__((ext_vector_type(4)));

__device__ inline void gld16(const void* g, void* l) {
  __builtin_amdgcn_global_load_lds(
      (__attribute__((address_space(1))) void*)g,
      (__attribute__((address_space(3))) void*)l, 16, 0, 0);
}

// ---------------- Router: one wave per token ----------------
__global__ __launch_bounds__(256) void router_kernel(
    const float* __restrict__ x, const float* __restrict__ wr,
    int* __restrict__ eidx, float* __restrict__ eprob) {
  int t = blockIdx.x * 4 + (threadIdx.x >> 6);
  int lane = threadIdx.x & 63;
  float acc[NEXP];
#pragma unroll
  for (int e = 0; e < NEXP; ++e) acc[e] = 0.f;
  const float4* xp = (const float4*)(x + (size_t)t * HDIM + lane * 16);
#pragma unroll
  for (int q = 0; q < 4; ++q) {
    float4 xv = xp[q];
    float xa[4] = {xv.x, xv.y, xv.z, xv.w};
#pragma unroll
    for (int ii = 0; ii < 4; ++ii) {
      int h = lane * 16 + q * 4 + ii;
      const float4* wp = (const float4*)(wr + (size_t)h * NEXP);
      float w[NEXP];
      float4 w0 = wp[0], w1 = wp[1], w2 = wp[2], w3 = wp[3];
      w[0]=w0.x; w[1]=w0.y; w[2]=w0.z; w[3]=w0.w;
      w[4]=w1.x; w[5]=w1.y; w[6]=w1.z; w[7]=w1.w;
      w[8]=w2.x; w[9]=w2.y; w[10]=w2.z; w[11]=w2.w;
      w[12]=w3.x; w[13]=w3.y; w[14]=w3.z; w[15]=w3.w;
#pragma unroll
      for (int e = 0; e < NEXP; ++e) acc[e] += xa[ii] * w[e];
    }
  }
#pragma unroll
  for (int e = 0; e < NEXP; ++e) {
#pragma unroll
    for (int s = 32; s > 0; s >>= 1) acc[e] += __shfl_xor(acc[e], s);
  }
  if (lane == 0) {
    float l0 = -1e30f, l1 = -1e30f; int i0 = 0, i1 = 0;
#pragma unroll
    for (int e = 0; e < NEXP; ++e) {
      float v = acc[e];
      if (v > l0) { l1 = l0; i1 = i0; l0 = v; i0 = e; }
      else if (v > l1) { l1 = v; i1 = e; }
    }
    float p0 = 1.f / (1.f + __expf(l1 - l0));  // == softmax-then-renorm over top2
    eidx[t * 2 + 0] = i0; eidx[t * 2 + 1] = i1;
    eprob[t * 2 + 0] = p0; eprob[t * 2 + 1] = 1.f - p0;
  }
}

// ------------- Positions: single block, deterministic prefix count -------------
__global__ __launch_bounds__(256) void pos_kernel(
    const int* __restrict__ eidx, const float* __restrict__ eprob,
    int* __restrict__ slot_token, float* __restrict__ slot_prob) {
  __shared__ int scan[256][NEXP];
  int tid = threadIdx.x;
  int cnt[NEXP];
#pragma unroll
  for (int e = 0; e < NEXP; ++e) cnt[e] = 0;
  int base_i = tid * 64;
  const int4* ep = (const int4*)(eidx + base_i);
  for (int i = 0; i < 16; ++i) {
    int4 v = ep[i];
    cnt[v.x]++; cnt[v.y]++; cnt[v.z]++; cnt[v.w]++;
  }
#pragma unroll
  for (int e = 0; e < NEXP; ++e) scan[tid][e] = cnt[e];
  __syncthreads();
  if (tid < NEXP) {
    int run = 0;
    for (int i = 0; i < 256; ++i) { int v = scan[i][tid]; scan[i][tid] = run; run += v; }
  }
  __syncthreads();
  int basec[NEXP];
#pragma unroll
  for (int e = 0; e < NEXP; ++e) basec[e] = scan[tid][e];
  for (int i = 0; i < 64; ++i) {
    int fi = base_i + i;
    int e = eidx[fi];
    int p = basec[e]++;
    if (p < CAP) {
      slot_token[e * CAP + p] = fi >> 1;   // token id
      slot_prob[e * CAP + p] = eprob[fi];
    }
  }
}

// ------------- Scatter x rows into bf16 dispatch buffer (zeros for empty) -------------
__global__ __launch_bounds__(256) void scatter_kernel(
    const float* __restrict__ x, const int* __restrict__ slot_token,
    __bf16* __restrict__ disp) {
  int s = blockIdx.x * 4 + (threadIdx.x >> 6);
  int lane = threadIdx.x & 63;
  int tok = slot_token[s];
  __bf16 vals[16] __attribute__((aligned(16)));
  if (tok >= 0) {
    const float4* xp = (const float4*)(x + (size_t)tok * HDIM + lane * 16);
#pragma unroll
    for (int q = 0; q < 4; ++q) {
      float4 v = xp[q];
      vals[q * 4 + 0] = (__bf16)v.x; vals[q * 4 + 1] = (__bf16)v.y;
      vals[q * 4 + 2] = (__bf16)v.z; vals[q * 4 + 3] = (__bf16)v.w;
    }
  } else {
#pragma unroll
    for (int q = 0; q < 16; ++q) vals[q] = (__bf16)0.f;
  }
  uint4* dst = (uint4*)(disp + (size_t)s * HDIM + lane * 16);
  dst[0] = ((uint4*)vals)[0];
  dst[1] = ((uint4*)vals)[1];
}

// ------------- Transpose + fp32->bf16 cast: (R,Cc) -> (Cc,R), per expert -------------
__global__ __launch_bounds__(256) void transpose_cast_kernel(
    const float* __restrict__ src, __bf16* __restrict__ dst, int R, int Cc) {
  int e = blockIdx.z;
  src += (size_t)e * R * Cc;
  dst += (size_t)e * R * Cc;
  __shared__ float tile[64][65];
  int gy = blockIdx.y * 64;  // src row base
  int gx = blockIdx.x * 64;  // src col base
  int tid = threadIdx.x;
  int r = tid >> 4;
  int c4 = (tid & 15) * 4;
#pragma unroll
  for (int rr = 0; rr < 4; ++rr) {
    float4 v = *(const float4*)(src + (size_t)(gy + r + rr * 16) * Cc + gx + c4);
    tile[r + rr * 16][c4 + 0] = v.x;
    tile[r + rr * 16][c4 + 1] = v.y;
    tile[r + rr * 16][c4 + 2] = v.z;
    tile[r + rr * 16][c4 + 3] = v.w;
  }
  __syncthreads();
  int r2 = tid >> 2;          // out row (= src col) 0..63
  int cb = (tid & 3) * 16;    // out col chunk
  __bf16 o[16] __attribute__((aligned(16)));
#pragma unroll
  for (int i = 0; i < 16; ++i) o[i] = (__bf16)tile[cb + i][r2];
  uint4* dp = (uint4*)(dst + (size_t)(gx + r2) * R + gy + cb);
  dp[0] = ((uint4*)o)[0];
  dp[1] = ((uint4*)o)[1];
}

// ------------- MFMA GEMM: 256x256 tile, BK=32, 4-deep LDS ring, 128KB LDS -------------
// A: (M,K) row-major bf16, Bt: (N,K) row-major bf16, per-expert contiguous.
// 8 waves (2M x 4N), per-wave output 128x64 = 8x4 16x16 frags (acc = 128 VGPR).
// 4 ring buffers x 32KB = 128KB -> 1 block/CU; __launch_bounds__(512,2) caps
// VGPR at 256 (need ~200 incl. av/bv -> no spills expected; spill tell-tale is
// WRITE_SIZE inflation).
// Prefetch depth 3 (counted vmcnt, never 0 in steady state): at iter kt we wait
// vmcnt(8) -> retires exactly stage(kt) (4 loads, issued 3 iterations ago);
// stage(kt+1),stage(kt+2) remain in flight across the barrier (T4).
// WAR ledger: stage(kt+3) writes buf[(kt+3)&3] == buf[(kt-1)&3], the buffer
// computed at iter kt-1. Every wave consumed its kt-1 ds_reads (MFMA data dep
// forces lgkmcnt) before reaching this barrier, and the stage is issued after
// the barrier -> no race. Same proof as the verified 3-buffer version, 1 deeper.
// LDS rows are 64B: 16B-chunk XOR swizzle with (row>>1)&3 applied to the global
// SOURCE address and the fragment reads (both-sides swizzle; measured 0 bank
// conflicts in the 128^2 version — formula unchanged).
// KSPLIT: split-K for GEMM2 (N=1024 -> only 320 blocks at 1/CU = 62% machine
// util; split-K=2 -> 640 blocks = 83%). Epilogue is atomicAdd so split-K is
// free; bias added only by split ks==0.
template <int EPI, int KSPLIT>
__global__ __launch_bounds__(512, 2) void moe_gemm_kernel(
    const __bf16* __restrict__ A, const __bf16* __restrict__ Bt,
    const float* __restrict__ bias, __bf16* __restrict__ Hout,
    const int* __restrict__ slot_token, const float* __restrict__ slot_prob,
    float* __restrict__ out, int M, int N, int Kd) {
  const int e  = blockIdx.z / KSPLIT;
  const int ks = blockIdx.z % KSPLIT;
  const int m0 = blockIdx.y * 256, n0 = blockIdx.x * 256;
  const __bf16* Ae = A + (size_t)e * M * Kd;
  const __bf16* Be = Bt + (size_t)e * N * Kd;
  __shared__ __bf16 lds[4 * 16384];  // 4 ring bufs x (A 8192 + B 8192 elems) = 128KB
  const int tid = threadIdx.x, wave = tid >> 6, lane = tid & 63;
  const int quad = lane >> 4, l15 = lane & 15;
  const int wm = (wave >> 2) * 128, wn = (wave & 3) * 64;
  f32x4 acc[8][4] = {};
  const int Kb = Kd * 2;                      // full row bytes
  const int ktiles = (Kd / KSPLIT) >> 5;      // K-tiles of 32 for this split
  const int kbase = ks * (Kd / KSPLIT) * 2;   // byte offset of this split's K range

  // Per-lane staging geometry (constant). Tile row = 64B (32 bf16), 4 x 16B chunks.
  // Each wave stages 2KB of A and 2KB of B per K-tile (2 gld16 each).
  const int bofs0 = wave * 2048;              // wave-uniform byte base in tile region
  int srow[2], sgcol[2];
#pragma unroll
  for (int rr = 0; rr < 2; ++rr) {
    int lofs = bofs0 + rr * 1024 + lane * 16;
    int row = lofs >> 6;                      // tile-local row
    int chunk = (lofs >> 4) & 3;              // 16B chunk within row (LDS dest)
    srow[rr] = row;
    sgcol[rr] = (chunk ^ ((row >> 1) & 3)) * 16; // swizzled source col (bytes)
  }

  auto stage = [&](int kt) {
    char* dstA = (char*)lds + (kt & 3) * 32768;
    char* dstB = dstA + 16384;
#pragma unroll
    for (int rr = 0; rr < 2; ++rr) {
      int bofs = bofs0 + rr * 1024;
      gld16((const char*)Ae + (size_t)(m0 + srow[rr]) * Kb + kbase + kt * 64 + sgcol[rr],
            dstA + bofs);
      gld16((const char*)Be + (size_t)(n0 + srow[rr]) * Kb + kbase + kt * 64 + sgcol[rr],
            dstB + bofs);
    }
  };

  stage(0);
  if (ktiles > 1) stage(1);
  if (ktiles > 2) stage(2);
  for (int kt = 0; kt < ktiles; ++kt) {
    // stages in flight before wait = min(3, ktiles-kt); retire exactly stage(kt)
    int rem = ktiles - kt;
    if (rem >= 3)      __builtin_amdgcn_s_waitcnt(0x0f78);  // vmcnt(8)
    else if (rem == 2) __builtin_amdgcn_s_waitcnt(0x0f74);  // vmcnt(4)
    else               __builtin_amdgcn_s_waitcnt(0x0f70);  // vmcnt(0)
    __builtin_amdgcn_s_barrier();
    if (kt + 3 < ktiles) stage(kt + 3);
    const __bf16* La = lds + (kt & 3) * 16384;
    const __bf16* Lb = La + 8192;
    bf16x8 av[8], bv[4];
#pragma unroll
    for (int i = 0; i < 8; ++i) {
      int r = wm + i * 16 + l15;
      av[i] = *(const bf16x8*)&La[r * 32 + ((quad ^ ((r >> 1) & 3)) << 3)];
    }
#pragma unroll
    for (int j = 0; j < 4; ++j) {
      int r = wn + j * 16 + l15;
      bv[j] = *(const bf16x8*)&Lb[r * 32 + ((quad ^ ((r >> 1) & 3)) << 3)];
    }
#pragma unroll
    for (int i = 0; i < 8; ++i)
#pragma unroll
      for (int j = 0; j < 4; ++j)
        acc[i][j] = __builtin_amdgcn_mfma_f32_16x16x32_bf16(av[i], bv[j], acc[i][j], 0, 0, 0);
  }
  // Epilogue. C/D layout: col = lane&15, row = quad*4 + reg  [verified m89/m91]
  if (EPI == 1) {
    __bf16* He = Hout + (size_t)e * M * N;
    float bj[4];
#pragma unroll
    for (int j = 0; j < 4; ++j) bj[j] = bias[(size_t)e * N + n0 + wn + j * 16 + l15];
#pragma unroll
    for (int i = 0; i < 8; ++i) {
#pragma unroll
      for (int r = 0; r < 4; ++r) {
        int m = m0 + wm + i * 16 + quad * 4 + r;
#pragma unroll
        for (int j = 0; j < 4; ++j) {
          int n = n0 + wn + j * 16 + l15;
          float v = acc[i][j][r] + bj[j];
          // tanh-approx GELU (JAX default approximate=True)
          float u = 0.7978845608028654f * (v + 0.044715f * v * v * v);
          float ex = __expf(-2.f * fabsf(u));
          float th = (1.f - ex) / (1.f + ex);
          th = copysignf(th, u);
          He[(size_t)m * N + n] = (__bf16)(0.5f * v * (1.f + th));
        }
      }
    }
  } else {
    const int* st = slot_token + e * CAP;
    const float* sp = slot_prob + e * CAP;
    float bj[4];
#pragma unroll
    for (int j = 0; j < 4; ++j)
      bj[j] = (ks == 0) ? bias[(size_t)e * N + n0 + wn + j * 16 + l15] : 0.f;
#pragma unroll
    for (int i = 0; i < 8; ++i) {
#pragma unroll
      for (int r = 0; r < 4; ++r) {
        int m = m0 + wm + i * 16 + quad * 4 + r;
        int tok = st[m];
        if (tok >= 0) {
          float p = sp[m];
#pragma unroll
          for (int j = 0; j < 4; ++j) {
            int n = n0 + wn + j * 16 + l15;
            float v = acc[i][j][r] + bj[j];
            atomicAdd(out + (size_t)tok * HDIM + n, p * v);
          }
        }
      }
    }
  }
}

extern "C" void kernel_launch(void* const* d_in, const int* in_sizes, int n_in,
                              void* d_out, int out_size, void* d_ws, size_t ws_size,
                              hipStream_t stream) {
  const float* x  = (const float*)d_in[0];
  const float* wr = (const float*)d_in[1];
  const float* w1 = (const float*)d_in[2];
  const float* b1 = (const float*)d_in[3];
  const float* w2 = (const float*)d_in[4];
  const float* b2 = (const float*)d_in[5];
  float* out = (float*)d_out;

  // Workspace layout (bytes)
  char* ws = (char*)d_ws;
  size_t off = 0;
  __bf16* w1t = (__bf16*)(ws + off); off += (size_t)NEXP * FDIM * HDIM * 2;   // 64MB (E,F,H)
  __bf16* w2t = (__bf16*)(ws + off); off += (size_t)NEXP * HDIM * FDIM * 2;   // 64MB (E,H,F)
  __bf16* disp = (__bf16*)(ws + off); off += (size_t)NEXP * CAP * HDIM * 2;   // 40MB (E*C,H)
  __bf16* hbuf = (__bf16*)(ws + off); off += (size_t)NEXP * CAP * FDIM * 2;   // 80MB (E*C,F)
  int*   slot_token = (int*)(ws + off);  off += (size_t)NEXP * CAP * 4;
  float* slot_prob  = (float*)(ws + off); off += (size_t)NEXP * CAP * 4;
  int*   eidx  = (int*)(ws + off);  off += (size_t)T_TOK * 2 * 4;
  float* eprob = (float*)(ws + off); off += (size_t)T_TOK * 2 * 4;
  if (ws_size < off) return;  // insufficient scratch

  // Init: empty slots = -1, output accumulates via atomics
  hipMemsetAsync(slot_token, 0xFF, (size_t)NEXP * CAP * 4, stream);
  hipMemsetAsync(d_out, 0, (size_t)T_TOK * HDIM * 4, stream);

  // Weight transpose+cast: w1 (E,H,F)->(E,F,H), w2 (E,F,H)->(E,H,F)
  transpose_cast_kernel<<<dim3(FDIM / 64, HDIM / 64, NEXP), 256, 0, stream>>>(w1, w1t, HDIM, FDIM);
  transpose_cast_kernel<<<dim3(HDIM / 64, FDIM / 64, NEXP), 256, 0, stream>>>(w2, w2t, FDIM, HDIM);

  // Routing
  router_kernel<<<T_TOK / 4, 256, 0, stream>>>(x, wr, eidx, eprob);
  pos_kernel<<<1, 256, 0, stream>>>(eidx, eprob, slot_token, slot_prob);
  scatter_kernel<<<NEXP * CAP / 4, 256, 0, stream>>>(x, slot_token, disp);

  // Expert FFN: 256x256 tiles. GEMM1 grid 8x5x16=640 blocks (1/CU -> 2.5 rounds).
  // GEMM2 with split-K=2: grid 4x5x32=640 blocks (vs 320 unsplit = 1.25-round tail).
  moe_gemm_kernel<1, 1><<<dim3(FDIM / 256, CAP / 256, NEXP), 512, 0, stream>>>(
      disp, w1t, b1, hbuf, nullptr, nullptr, nullptr, CAP, FDIM, HDIM);
  moe_gemm_kernel<2, 2><<<dim3(HDIM / 256, CAP / 256, NEXP * 2), 512, 0, stream>>>(
      hbuf, w2t, b2, nullptr, slot_token, slot_prob, out, CAP, HDIM, FDIM);
}

// Round 2
// 780.193 us; speedup vs baseline: 1.0229x; 1.0229x over previous
//
#include <hip/hip_runtime.h>
#include <cstdint>
#include <cstddef>

// Problem constants
#define T_TOK 8192
#define HDIM  1024
#define FDIM  2048
#define NEXP  16
#define CAP   1280

typedef __bf16 bf16x8 __attribute__((ext_vector_type(8)));
typedef float  f32x4  __attribute__((ext_vector_type(4)));

__device__ inline void gld16(const void* g, void* l) {
  __builtin_amdgcn_global_load_lds(
      (__attribute__((address_space(1))) void*)g,
      (__attribute__((address_space(3))) void*)l, 16, 0, 0);
}

// ---------------- Router: one wave per token ----------------
__global__ __launch_bounds__(256) void router_kernel(
    const float* __restrict__ x, const float* __restrict__ wr,
    int* __restrict__ eidx, float* __restrict__ eprob) {
  int t = blockIdx.x * 4 + (threadIdx.x >> 6);
  int lane = threadIdx.x & 63;
  float acc[NEXP];
#pragma unroll
  for (int e = 0; e < NEXP; ++e) acc[e] = 0.f;
  const float4* xp = (const float4*)(x + (size_t)t * HDIM + lane * 16);
#pragma unroll
  for (int q = 0; q < 4; ++q) {
    float4 xv = xp[q];
    float xa[4] = {xv.x, xv.y, xv.z, xv.w};
#pragma unroll
    for (int ii = 0; ii < 4; ++ii) {
      int h = lane * 16 + q * 4 + ii;
      const float4* wp = (const float4*)(wr + (size_t)h * NEXP);
      float w[NEXP];
      float4 w0 = wp[0], w1 = wp[1], w2 = wp[2], w3 = wp[3];
      w[0]=w0.x; w[1]=w0.y; w[2]=w0.z; w[3]=w0.w;
      w[4]=w1.x; w[5]=w1.y; w[6]=w1.z; w[7]=w1.w;
      w[8]=w2.x; w[9]=w2.y; w[10]=w2.z; w[11]=w2.w;
      w[12]=w3.x; w[13]=w3.y; w[14]=w3.z; w[15]=w3.w;
#pragma unroll
      for (int e = 0; e < NEXP; ++e) acc[e] += xa[ii] * w[e];
    }
  }
#pragma unroll
  for (int e = 0; e < NEXP; ++e) {
#pragma unroll
    for (int s = 32; s > 0; s >>= 1) acc[e] += __shfl_xor(acc[e], s);
  }
  if (lane == 0) {
    float l0 = -1e30f, l1 = -1e30f; int i0 = 0, i1 = 0;
#pragma unroll
    for (int e = 0; e < NEXP; ++e) {
      float v = acc[e];
      if (v > l0) { l1 = l0; i1 = i0; l0 = v; i0 = e; }
      else if (v > l1) { l1 = v; i1 = e; }
    }
    float p0 = 1.f / (1.f + __expf(l1 - l0));  // == softmax-then-renorm over top2
    eidx[t * 2 + 0] = i0; eidx[t * 2 + 1] = i1;
    eprob[t * 2 + 0] = p0; eprob[t * 2 + 1] = 1.f - p0;
  }
}

// ------------- Positions: single block, deterministic prefix count -------------
__global__ __launch_bounds__(256) void pos_kernel(
    const int* __restrict__ eidx, const float* __restrict__ eprob,
    int* __restrict__ slot_token, float* __restrict__ slot_prob) {
  __shared__ int scan[256][NEXP];
  int tid = threadIdx.x;
  int cnt[NEXP];
#pragma unroll
  for (int e = 0; e < NEXP; ++e) cnt[e] = 0;
  int base_i = tid * 64;
  const int4* ep = (const int4*)(eidx + base_i);
  for (int i = 0; i < 16; ++i) {
    int4 v = ep[i];
    cnt[v.x]++; cnt[v.y]++; cnt[v.z]++; cnt[v.w]++;
  }
#pragma unroll
  for (int e = 0; e < NEXP; ++e) scan[tid][e] = cnt[e];
  __syncthreads();
  if (tid < NEXP) {
    int run = 0;
    for (int i = 0; i < 256; ++i) { int v = scan[i][tid]; scan[i][tid] = run; run += v; }
  }
  __syncthreads();
  int basec[NEXP];
#pragma unroll
  for (int e = 0; e < NEXP; ++e) basec[e] = scan[tid][e];
  for (int i = 0; i < 64; ++i) {
    int fi = base_i + i;
    int e = eidx[fi];
    int p = basec[e]++;
    if (p < CAP) {
      slot_token[e * CAP + p] = fi >> 1;   // token id
      slot_prob[e * CAP + p] = eprob[fi];
    }
  }
}

// ------------- Scatter x rows into bf16 dispatch buffer (zeros for empty) -------------
__global__ __launch_bounds__(256) void scatter_kernel(
    const float* __restrict__ x, const int* __restrict__ slot_token,
    __bf16* __restrict__ disp) {
  int s = blockIdx.x * 4 + (threadIdx.x >> 6);
  int lane = threadIdx.x & 63;
  int tok = slot_token[s];
  __bf16 vals[16] __attribute__((aligned(16)));
  if (tok >= 0) {
    const float4* xp = (const float4*)(x + (size_t)tok * HDIM + lane * 16);
#pragma unroll
    for (int q = 0; q < 4; ++q) {
      float4 v = xp[q];
      vals[q * 4 + 0] = (__bf16)v.x; vals[q * 4 + 1] = (__bf16)v.y;
      vals[q * 4 + 2] = (__bf16)v.z; vals[q * 4 + 3] = (__bf16)v.w;
    }
  } else {
#pragma unroll
    for (int q = 0; q < 16; ++q) vals[q] = (__bf16)0.f;
  }
  uint4* dst = (uint4*)(disp + (size_t)s * HDIM + lane * 16);
  dst[0] = ((uint4*)vals)[0];
  dst[1] = ((uint4*)vals)[1];
}

// ------------- Transpose + fp32->bf16 cast: (R,Cc) -> (Cc,R), per expert -------------
__global__ __launch_bounds__(256) void transpose_cast_kernel(
    const float* __restrict__ src, __bf16* __restrict__ dst, int R, int Cc) {
  int e = blockIdx.z;
  src += (size_t)e * R * Cc;
  dst += (size_t)e * R * Cc;
  __shared__ float tile[64][65];
  int gy = blockIdx.y * 64;  // src row base
  int gx = blockIdx.x * 64;  // src col base
  int tid = threadIdx.x;
  int r = tid >> 4;
  int c4 = (tid & 15) * 4;
#pragma unroll
  for (int rr = 0; rr < 4; ++rr) {
    float4 v = *(const float4*)(src + (size_t)(gy + r + rr * 16) * Cc + gx + c4);
    tile[r + rr * 16][c4 + 0] = v.x;
    tile[r + rr * 16][c4 + 1] = v.y;
    tile[r + rr * 16][c4 + 2] = v.z;
    tile[r + rr * 16][c4 + 3] = v.w;
  }
  __syncthreads();
  int r2 = tid >> 2;          // out row (= src col) 0..63
  int cb = (tid & 3) * 16;    // out col chunk
  __bf16 o[16] __attribute__((aligned(16)));
#pragma unroll
  for (int i = 0; i < 16; ++i) o[i] = (__bf16)tile[cb + i][r2];
  uint4* dp = (uint4*)(dst + (size_t)(gx + r2) * R + gy + cb);
  dp[0] = ((uint4*)o)[0];
  dp[1] = ((uint4*)o)[1];
}

// ------------- MFMA GEMM: 256x256 tile, BK=64, 2-phase double-buffer, 128KB LDS -----
// m248v2-proven schedule (grouped GEMM @ K=1024, 256^2, 2ph = 655-666 TF):
//   prologue: stage(0); vmcnt(0); barrier;
//   iter t:   stage(t+1)   <- issued FIRST, lands during the ~2000-cyc MFMA phase
//             ds_read kk0 (12 b128) ; MFMA kk0 (32) ; ds_read kk1 ; MFMA kk1
//               (compiler inserts counted lgkmcnt; kk1 reads overlap kk0 MFMAs)
//             vmcnt(0); barrier;    <- single sync point per K-tile, drain is cheap
// T5: setprio(1) around each MFMA cluster.
// WAR ledger: stage(t+1) writes buf[(t+1)&1], last READ at iter t-1; those ds_reads
// are drained (lgkm waits precede their MFMA uses) before the end-of-(t-1) barrier,
// and stage(t+1) issues after it -> no race. vmcnt(0)+barrier at end of t ensures
// buf[(t+1)&1] is fully landed before any wave reads it at t+1.
// LDS rows are 128B (BK=64): 16B-chunk swizzle chunk^=(row&7), applied to the
// global SOURCE (gld16 dest stays linear, rule #21) and to fragment reads.
// Bank check: per 16B granule, 8 lanes on 8 distinct rows; all 32 banks uniformly
// busy -> 8 cyc = 1024B/128B minimum, conflict-free.
// KSPLIT: split-K for GEMM2 (320 blocks -> 62% tail util; x2 -> 640 = 83%).
// Epilogue is atomicAdd so split-K is free; bias added only by split ks==0.
template <int EPI, int KSPLIT>
__global__ __launch_bounds__(512, 2) void moe_gemm_kernel(
    const __bf16* __restrict__ A, const __bf16* __restrict__ Bt,
    const float* __restrict__ bias, __bf16* __restrict__ Hout,
    const int* __restrict__ slot_token, const float* __restrict__ slot_prob,
    float* __restrict__ out, int M, int N, int Kd) {
  const int e  = blockIdx.z / KSPLIT;
  const int ks = blockIdx.z % KSPLIT;
  const int m0 = blockIdx.y * 256, n0 = blockIdx.x * 256;
  const char* Ae = (const char*)A + (size_t)e * M * Kd * 2;
  const char* Be = (const char*)Bt + (size_t)e * N * Kd * 2;
  __shared__ __bf16 lds[2 * 32768];  // 2 bufs x (A 256x64 + B 256x64) bf16 = 128KB
  const int tid = threadIdx.x, wave = tid >> 6, lane = tid & 63;
  const int quad = lane >> 4, l15 = lane & 15;
  const int wm = (wave >> 2) * 128, wn = (wave & 3) * 64;
  f32x4 acc[8][4] = {};
  const size_t Kb = (size_t)Kd * 2;           // full row bytes
  const int ktiles = (Kd / KSPLIT) >> 6;      // K-tiles of 64 for this split
  const int kbase = ks * (Kd / KSPLIT) * 2;   // byte offset of this split's K range

  // Staging: per K-tile each thread moves 4x16B of A and 4x16B of B.
  // Dest (linear, tile-local): tid*16 + j*8192  -> row=(tid>>3)+j*64, chunk=tid&7.
  // Source chunk pre-swizzled: chunk ^ (row&7), row&7 == (tid>>3)&7 for all j.
  const int rbase = tid >> 3;
  const int scol  = ((tid & 7) ^ ((tid >> 3) & 7)) * 16;
  const char* srcA = Ae + (size_t)(m0 + rbase) * Kb + kbase + scol;
  const char* srcB = Be + (size_t)(n0 + rbase) * Kb + kbase + scol;
  const size_t rstep = 64 * Kb;               // 64 rows per j-round
  const int dofs = tid * 16;

  auto stage = [&](int t) {
    char* base = (char*)lds + (t & 1) * 65536;
#pragma unroll
    for (int j = 0; j < 4; ++j)
      gld16(srcA + (size_t)t * 128 + j * rstep, base + dofs + j * 8192);
#pragma unroll
    for (int j = 0; j < 4; ++j)
      gld16(srcB + (size_t)t * 128 + j * rstep, base + 32768 + dofs + j * 8192);
  };

  // Fragment read offsets (bytes, tile-local), constant per thread.
  // True chunk for (kk,quad) = kk*4+quad; swizzled with row&7 == l15&7.
  int aoff[8], boff[4], coff[2];
#pragma unroll
  for (int i = 0; i < 8; ++i) aoff[i] = (wm + i * 16 + l15) * 128;
#pragma unroll
  for (int j = 0; j < 4; ++j) boff[j] = (wn + j * 16 + l15) * 128;
#pragma unroll
  for (int kk = 0; kk < 2; ++kk) coff[kk] = (((kk * 4 + quad) ^ (l15 & 7)) * 16);

  stage(0);
  __builtin_amdgcn_s_waitcnt(0x0f70);  // vmcnt(0)
  __builtin_amdgcn_s_barrier();
  for (int t = 0; t < ktiles; ++t) {
    if (t + 1 < ktiles) stage(t + 1);
    const char* La = (const char*)lds + (t & 1) * 65536;
    const char* Lb = La + 32768;
#pragma unroll
    for (int kk = 0; kk < 2; ++kk) {
      bf16x8 av[8], bv[4];
#pragma unroll
      for (int i = 0; i < 8; ++i) av[i] = *(const bf16x8*)(La + aoff[i] + coff[kk]);
#pragma unroll
      for (int j = 0; j < 4; ++j) bv[j] = *(const bf16x8*)(Lb + boff[j] + coff[kk]);
      __builtin_amdgcn_s_setprio(1);
#pragma unroll
      for (int i = 0; i < 8; ++i)
#pragma unroll
        for (int j = 0; j < 4; ++j)
          acc[i][j] = __builtin_amdgcn_mfma_f32_16x16x32_bf16(av[i], bv[j], acc[i][j], 0, 0, 0);
      __builtin_amdgcn_s_setprio(0);
    }
    if (t + 1 < ktiles) __builtin_amdgcn_s_waitcnt(0x0f70);  // vmcnt(0): buf landed
    __builtin_amdgcn_s_barrier();
  }
  // Epilogue. C/D layout: col = lane&15, row = quad*4 + reg  [verified m89/m91]
  if (EPI == 1) {
    __bf16* He = Hout + (size_t)e * M * N;
    float bj[4];
#pragma unroll
    for (int j = 0; j < 4; ++j) bj[j] = bias[(size_t)e * N + n0 + wn + j * 16 + l15];
#pragma unroll
    for (int i = 0; i < 8; ++i) {
#pragma unroll
      for (int r = 0; r < 4; ++r) {
        int m = m0 + wm + i * 16 + quad * 4 + r;
#pragma unroll
        for (int j = 0; j < 4; ++j) {
          int n = n0 + wn + j * 16 + l15;
          float v = acc[i][j][r] + bj[j];
          // tanh-approx GELU (JAX default approximate=True)
          float u = 0.7978845608028654f * (v + 0.044715f * v * v * v);
          float ex = __expf(-2.f * fabsf(u));
          float th = (1.f - ex) / (1.f + ex);
          th = copysignf(th, u);
          He[(size_t)m * N + n] = (__bf16)(0.5f * v * (1.f + th));
        }
      }
    }
  } else {
    const int* st = slot_token + e * CAP;
    const float* sp = slot_prob + e * CAP;
    float bj[4];
#pragma unroll
    for (int j = 0; j < 4; ++j)
      bj[j] = (ks == 0) ? bias[(size_t)e * N + n0 + wn + j * 16 + l15] : 0.f;
#pragma unroll
    for (int i = 0; i < 8; ++i) {
#pragma unroll
      for (int r = 0; r < 4; ++r) {
        int m = m0 + wm + i * 16 + quad * 4 + r;
        int tok = st[m];
        if (tok >= 0) {
          float p = sp[m];
#pragma unroll
          for (int j = 0; j < 4; ++j) {
            int n = n0 + wn + j * 16 + l15;
            float v = acc[i][j][r] + bj[j];
            atomicAdd(out + (size_t)tok * HDIM + n, p * v);
          }
        }
      }
    }
  }
}

extern "C" void kernel_launch(void* const* d_in, const int* in_sizes, int n_in,
                              void* d_out, int out_size, void* d_ws, size_t ws_size,
                              hipStream_t stream) {
  const float* x  = (const float*)d_in[0];
  const float* wr = (const float*)d_in[1];
  const float* w1 = (const float*)d_in[2];
  const float* b1 = (const float*)d_in[3];
  const float* w2 = (const float*)d_in[4];
  const float* b2 = (const float*)d_in[5];
  float* out = (float*)d_out;

  // Workspace layout (bytes)
  char* ws = (char*)d_ws;
  size_t off = 0;
  __bf16* w1t = (__bf16*)(ws + off); off += (size_t)NEXP * FDIM * HDIM * 2;   // 64MB (E,F,H)
  __bf16* w2t = (__bf16*)(ws + off); off += (size_t)NEXP * HDIM * FDIM * 2;   // 64MB (E,H,F)
  __bf16* disp = (__bf16*)(ws + off); off += (size_t)NEXP * CAP * HDIM * 2;   // 40MB (E*C,H)
  __bf16* hbuf = (__bf16*)(ws + off); off += (size_t)NEXP * CAP * FDIM * 2;   // 80MB (E*C,F)
  int*   slot_token = (int*)(ws + off);  off += (size_t)NEXP * CAP * 4;
  float* slot_prob  = (float*)(ws + off); off += (size_t)NEXP * CAP * 4;
  int*   eidx  = (int*)(ws + off);  off += (size_t)T_TOK * 2 * 4;
  float* eprob = (float*)(ws + off); off += (size_t)T_TOK * 2 * 4;
  if (ws_size < off) return;  // insufficient scratch

  // Init: empty slots = -1, output accumulates via atomics
  hipMemsetAsync(slot_token, 0xFF, (size_t)NEXP * CAP * 4, stream);
  hipMemsetAsync(d_out, 0, (size_t)T_TOK * HDIM * 4, stream);

  // Weight transpose+cast: w1 (E,H,F)->(E,F,H), w2 (E,F,H)->(E,H,F)
  transpose_cast_kernel<<<dim3(FDIM / 64, HDIM / 64, NEXP), 256, 0, stream>>>(w1, w1t, HDIM, FDIM);
  transpose_cast_kernel<<<dim3(HDIM / 64, FDIM / 64, NEXP), 256, 0, stream>>>(w2, w2t, FDIM, HDIM);

  // Routing
  router_kernel<<<T_TOK / 4, 256, 0, stream>>>(x, wr, eidx, eprob);
  pos_kernel<<<1, 256, 0, stream>>>(eidx, eprob, slot_token, slot_prob);
  scatter_kernel<<<NEXP * CAP / 4, 256, 0, stream>>>(x, slot_token, disp);

  // Expert FFN: 256x256 tiles, BK=64. GEMM1 grid 8x5x16=640 blocks (2.5 rounds).
  // GEMM2 split-K=2: grid 4x5x32=640 (vs 320 unsplit = 1.25-round tail).
  moe_gemm_kernel<1, 1><<<dim3(FDIM / 256, CAP / 256, NEXP), 512, 0, stream>>>(
      disp, w1t, b1, hbuf, nullptr, nullptr, nullptr, CAP, FDIM, HDIM);
  moe_gemm_kernel<2, 2><<<dim3(HDIM / 256, CAP / 256, NEXP * 2), 512, 0, stream>>>(
      hbuf, w2t, b2, nullptr, slot_token, slot_prob, out, CAP, HDIM, FDIM);
}

// Round 3
// 754.909 us; speedup vs baseline: 1.0572x; 1.0335x over previous
//
#include <hip/hip_runtime.h>
#include <cstdint>
#include <cstddef>

// Problem constants
#define T_TOK 8192
#define HDIM  1024
#define FDIM  2048
#define NEXP  16
#define CAP   1280

typedef __bf16 bf16x8 __attribute__((ext_vector_type(8)));
typedef float  f32x4  __attribute__((ext_vector_type(4)));

__device__ inline void gld16(const void* g, void* l) {
  __builtin_amdgcn_global_load_lds(
      (__attribute__((address_space(1))) void*)g,
      (__attribute__((address_space(3))) void*)l, 16, 0, 0);
}

// ---------------- Router: one wave per token ----------------
__global__ __launch_bounds__(256) void router_kernel(
    const float* __restrict__ x, const float* __restrict__ wr,
    int* __restrict__ eidx, float* __restrict__ eprob) {
  int t = blockIdx.x * 4 + (threadIdx.x >> 6);
  int lane = threadIdx.x & 63;
  float acc[NEXP];
#pragma unroll
  for (int e = 0; e < NEXP; ++e) acc[e] = 0.f;
  const float4* xp = (const float4*)(x + (size_t)t * HDIM + lane * 16);
#pragma unroll
  for (int q = 0; q < 4; ++q) {
    float4 xv = xp[q];
    float xa[4] = {xv.x, xv.y, xv.z, xv.w};
#pragma unroll
    for (int ii = 0; ii < 4; ++ii) {
      int h = lane * 16 + q * 4 + ii;
      const float4* wp = (const float4*)(wr + (size_t)h * NEXP);
      float w[NEXP];
      float4 w0 = wp[0], w1 = wp[1], w2 = wp[2], w3 = wp[3];
      w[0]=w0.x; w[1]=w0.y; w[2]=w0.z; w[3]=w0.w;
      w[4]=w1.x; w[5]=w1.y; w[6]=w1.z; w[7]=w1.w;
      w[8]=w2.x; w[9]=w2.y; w[10]=w2.z; w[11]=w2.w;
      w[12]=w3.x; w[13]=w3.y; w[14]=w3.z; w[15]=w3.w;
#pragma unroll
      for (int e = 0; e < NEXP; ++e) acc[e] += xa[ii] * w[e];
    }
  }
#pragma unroll
  for (int e = 0; e < NEXP; ++e) {
#pragma unroll
    for (int s = 32; s > 0; s >>= 1) acc[e] += __shfl_xor(acc[e], s);
  }
  if (lane == 0) {
    float l0 = -1e30f, l1 = -1e30f; int i0 = 0, i1 = 0;
#pragma unroll
    for (int e = 0; e < NEXP; ++e) {
      float v = acc[e];
      if (v > l0) { l1 = l0; i1 = i0; l0 = v; i0 = e; }
      else if (v > l1) { l1 = v; i1 = e; }
    }
    float p0 = 1.f / (1.f + __expf(l1 - l0));  // == softmax-then-renorm over top2
    eidx[t * 2 + 0] = i0; eidx[t * 2 + 1] = i1;
    eprob[t * 2 + 0] = p0; eprob[t * 2 + 1] = 1.f - p0;
  }
}

// ------------- Positions: single block, deterministic prefix count -------------
__global__ __launch_bounds__(256) void pos_kernel(
    const int* __restrict__ eidx, const float* __restrict__ eprob,
    int* __restrict__ slot_token, float* __restrict__ slot_prob) {
  __shared__ int scan[256][NEXP];
  int tid = threadIdx.x;
  int cnt[NEXP];
#pragma unroll
  for (int e = 0; e < NEXP; ++e) cnt[e] = 0;
  int base_i = tid * 64;
  const int4* ep = (const int4*)(eidx + base_i);
  for (int i = 0; i < 16; ++i) {
    int4 v = ep[i];
    cnt[v.x]++; cnt[v.y]++; cnt[v.z]++; cnt[v.w]++;
  }
#pragma unroll
  for (int e = 0; e < NEXP; ++e) scan[tid][e] = cnt[e];
  __syncthreads();
  if (tid < NEXP) {
    int run = 0;
    for (int i = 0; i < 256; ++i) { int v = scan[i][tid]; scan[i][tid] = run; run += v; }
  }
  __syncthreads();
  int basec[NEXP];
#pragma unroll
  for (int e = 0; e < NEXP; ++e) basec[e] = scan[tid][e];
  for (int i = 0; i < 64; ++i) {
    int fi = base_i + i;
    int e = eidx[fi];
    int p = basec[e]++;
    if (p < CAP) {
      slot_token[e * CAP + p] = fi >> 1;   // token id
      slot_prob[e * CAP + p] = eprob[fi];
    }
  }
}

// ------- Scatter x rows into K-CHUNKED bf16 dispatch buffer (zeros for empty) -------
// disp layout: [E][KA=16][CAP][64] — element (e, m, h) at ((e*16 + h/64)*CAP + m)*64 + h%64.
// Lane covers cols lane*16..lane*16+15, all inside chunk kt = lane>>2.
__global__ __launch_bounds__(256) void scatter_kernel(
    const float* __restrict__ x, const int* __restrict__ slot_token,
    __bf16* __restrict__ disp) {
  int s = blockIdx.x * 4 + (threadIdx.x >> 6);
  int lane = threadIdx.x & 63;
  int e = s / CAP, m = s % CAP;
  int tok = slot_token[s];
  __bf16 vals[16] __attribute__((aligned(16)));
  if (tok >= 0) {
    const float4* xp = (const float4*)(x + (size_t)tok * HDIM + lane * 16);
#pragma unroll
    for (int q = 0; q < 4; ++q) {
      float4 v = xp[q];
      vals[q * 4 + 0] = (__bf16)v.x; vals[q * 4 + 1] = (__bf16)v.y;
      vals[q * 4 + 2] = (__bf16)v.z; vals[q * 4 + 3] = (__bf16)v.w;
    }
  } else {
#pragma unroll
    for (int q = 0; q < 16; ++q) vals[q] = (__bf16)0.f;
  }
  uint4* dst = (uint4*)(disp + (((size_t)e * 16 + (lane >> 2)) * CAP + m) * 64 + (lane & 3) * 16);
  dst[0] = ((uint4*)vals)[0];
  dst[1] = ((uint4*)vals)[1];
}

// --- Transpose + fp32->bf16 cast into K-CHUNKED layout: (R,Cc) -> [R/64][Cc][64] ---
// Out element (row=src col in [0,Cc), col=src row in [0,R)) at ((col/64)*Cc + row)*64 + col%64.
__global__ __launch_bounds__(256) void transpose_cast_kernel(
    const float* __restrict__ src, __bf16* __restrict__ dst, int R, int Cc) {
  int e = blockIdx.z;
  src += (size_t)e * R * Cc;
  dst += (size_t)e * R * Cc;
  __shared__ float tile[64][65];
  int gy = blockIdx.y * 64;  // src row base (out col base)
  int gx = blockIdx.x * 64;  // src col base (out row base)
  int tid = threadIdx.x;
  int r = tid >> 4;
  int c4 = (tid & 15) * 4;
#pragma unroll
  for (int rr = 0; rr < 4; ++rr) {
    float4 v = *(const float4*)(src + (size_t)(gy + r + rr * 16) * Cc + gx + c4);
    tile[r + rr * 16][c4 + 0] = v.x;
    tile[r + rr * 16][c4 + 1] = v.y;
    tile[r + rr * 16][c4 + 2] = v.z;
    tile[r + rr * 16][c4 + 3] = v.w;
  }
  __syncthreads();
  int r2 = tid >> 2;          // out row offset (= src col) 0..63
  int cb = (tid & 3) * 16;    // out col chunk-offset within the 64-col chunk
  __bf16 o[16] __attribute__((aligned(16)));
#pragma unroll
  for (int i = 0; i < 16; ++i) o[i] = (__bf16)tile[cb + i][r2];
  // out col = gy + cb + i; chunk = gy>>6 (cb+i < 64); within-chunk = cb + i
  uint4* dp = (uint4*)(dst + ((size_t)(gy >> 6) * Cc + gx + r2) * 64 + cb);
  dp[0] = ((uint4*)o)[0];
  dp[1] = ((uint4*)o)[1];
}

// ------------- MFMA GEMM: 256x256 tile, BK=64, 2-phase double-buffer, 128KB LDS -----
// OPERANDS ARE K-CHUNKED: A = [e][Kd/64][M][64], Bt = [e][Kd/64][N][64] (bf16).
// Per K-tile a block stages a CONTIGUOUS 32KB A-slab-window + 32KB B-slab-window:
// every wave-level global_load_lds reads 1KB sequential -> full L2 lines, full DRAM
// pages. (Rounds 0-2 read 128B columns at 2KB stride -> delivery capped ~3 TB/s,
// HBM 1.8 TB/s; three different schedules all stuck at ~415 TF -> pattern, not
// schedule, was the limit.)
// Chunk-XOR swizzle (chunk ^= row&7) is applied in the SOURCE address (gld_lds dest
// stays linear, rule #21) and in fragment reads — identical LDS image to round 2
// (0 bank conflicts, verified pass).
// Schedule (unchanged, m248v2 2-phase): stage(t+1) first, ds_read+MFMA (setprio),
// vmcnt(0)+barrier once per tile. WAR ledger as before.
// XCD swizzle (bijective, nwg%8==0): work f runs on XCD f/(nwg/8) -> each XCD owns
// 2 experts; per-kt working set ~832KB << 4MB L2 -> compulsory-only HBM fetch.
// KSPLIT: split-K for GEMM2 tail (320 -> 640 blocks); atomicAdd makes it free;
// bias added only by ks==0.
template <int EPI, int KSPLIT>
__global__ __launch_bounds__(512, 2) void moe_gemm_kernel(
    const __bf16* __restrict__ A, const __bf16* __restrict__ Bt,
    const float* __restrict__ bias, __bf16* __restrict__ Hout,
    const int* __restrict__ slot_token, const float* __restrict__ slot_prob,
    float* __restrict__ out, int M, int N, int Kd) {
  // --- bijective chunked XCD swizzle ---
  const int nwg = gridDim.x * gridDim.y * gridDim.z;
  int flat = (blockIdx.z * gridDim.y + blockIdx.y) * gridDim.x + blockIdx.x;
  flat = (flat & 7) * (nwg >> 3) + (flat >> 3);
  const int bx = flat % gridDim.x;
  int tmpf = flat / gridDim.x;
  const int by = tmpf % gridDim.y;
  const int bz = tmpf / gridDim.y;

  const int e  = bz / KSPLIT;
  const int ks = bz % KSPLIT;
  const int m0 = by * 256, n0 = bx * 256;
  __shared__ __bf16 lds[2 * 32768];  // 2 bufs x (A 256x64 + B 256x64) bf16 = 128KB
  const int tid = threadIdx.x, wave = tid >> 6, lane = tid & 63;
  const int quad = lane >> 4, l15 = lane & 15;
  const int wm = (wave >> 2) * 128, wn = (wave & 3) * 64;
  f32x4 acc[8][4] = {};
  const int ktiles = (Kd / KSPLIT) >> 6;      // K-tiles of 64 for this split
  const size_t slabA = (size_t)M * 128;       // bytes per A K-slab
  const size_t slabB = (size_t)N * 128;       // bytes per B K-slab

  // Staging: per K-tile each thread moves 4x16B of A and 4x16B of B.
  // LDS dest (linear, tile-local): tid*16 + j*8192 -> row=(tid>>3)+j*64, chunk=tid&7.
  // Source: chunked slab, row-major 128B rows; chunk pre-swizzled with row&7.
  const int rbase = tid >> 3;
  const int swz = ((tid & 7) ^ (rbase & 7)) * 16;
  const char* srcA = (const char*)A + (size_t)e * (Kd >> 6) * slabA
                     + (size_t)(m0 + rbase) * 128 + swz;
  const char* srcB = (const char*)Bt + (size_t)e * (Kd >> 6) * slabB
                     + (size_t)(n0 + rbase) * 128 + swz;
  const int dofs = tid * 16;

  auto stage = [&](int t) {
    char* base = (char*)lds + (t & 1) * 65536;
    const char* sA = srcA + (size_t)(ks * ktiles + t) * slabA;
    const char* sB = srcB + (size_t)(ks * ktiles + t) * slabB;
#pragma unroll
    for (int j = 0; j < 4; ++j)
      gld16(sA + j * 8192, base + dofs + j * 8192);
#pragma unroll
    for (int j = 0; j < 4; ++j)
      gld16(sB + j * 8192, base + 32768 + dofs + j * 8192);
  };

  // Fragment read offsets (bytes, tile-local), constant per thread.
  // True chunk for (kk,quad) = kk*4+quad; swizzled with row&7 == l15&7.
  int aoff[8], boff[4], coff[2];
#pragma unroll
  for (int i = 0; i < 8; ++i) aoff[i] = (wm + i * 16 + l15) * 128;
#pragma unroll
  for (int j = 0; j < 4; ++j) boff[j] = (wn + j * 16 + l15) * 128;
#pragma unroll
  for (int kk = 0; kk < 2; ++kk) coff[kk] = (((kk * 4 + quad) ^ (l15 & 7)) * 16);

  stage(0);
  __builtin_amdgcn_s_waitcnt(0x0f70);  // vmcnt(0)
  __builtin_amdgcn_s_barrier();
  for (int t = 0; t < ktiles; ++t) {
    if (t + 1 < ktiles) stage(t + 1);
    const char* La = (const char*)lds + (t & 1) * 65536;
    const char* Lb = La + 32768;
#pragma unroll
    for (int kk = 0; kk < 2; ++kk) {
      bf16x8 av[8], bv[4];
#pragma unroll
      for (int i = 0; i < 8; ++i) av[i] = *(const bf16x8*)(La + aoff[i] + coff[kk]);
#pragma unroll
      for (int j = 0; j < 4; ++j) bv[j] = *(const bf16x8*)(Lb + boff[j] + coff[kk]);
      __builtin_amdgcn_s_setprio(1);
#pragma unroll
      for (int i = 0; i < 8; ++i)
#pragma unroll
        for (int j = 0; j < 4; ++j)
          acc[i][j] = __builtin_amdgcn_mfma_f32_16x16x32_bf16(av[i], bv[j], acc[i][j], 0, 0, 0);
      __builtin_amdgcn_s_setprio(0);
    }
    if (t + 1 < ktiles) __builtin_amdgcn_s_waitcnt(0x0f70);  // vmcnt(0): buf landed
    __builtin_amdgcn_s_barrier();
  }
  // Epilogue. C/D layout: col = lane&15, row = quad*4 + reg  [verified m89/m91]
  if (EPI == 1) {
    // Write Hout K-CHUNKED: [e][N/64][M][64]. Chunk = (n0+wn)>>6 (wave-uniform).
    __bf16* He = Hout + (size_t)e * M * N;
    const size_t kfbase = (size_t)((n0 + wn) >> 6) * M;
    float bj[4];
#pragma unroll
    for (int j = 0; j < 4; ++j) bj[j] = bias[(size_t)e * N + n0 + wn + j * 16 + l15];
#pragma unroll
    for (int i = 0; i < 8; ++i) {
#pragma unroll
      for (int r = 0; r < 4; ++r) {
        int m = m0 + wm + i * 16 + quad * 4 + r;
#pragma unroll
        for (int j = 0; j < 4; ++j) {
          float v = acc[i][j][r] + bj[j];
          // tanh-approx GELU (JAX default approximate=True)
          float u = 0.7978845608028654f * (v + 0.044715f * v * v * v);
          float ex = __expf(-2.f * fabsf(u));
          float th = (1.f - ex) / (1.f + ex);
          th = copysignf(th, u);
          He[(kfbase + m) * 64 + j * 16 + l15] = (__bf16)(0.5f * v * (1.f + th));
        }
      }
    }
  } else {
    const int* st = slot_token + e * CAP;
    const float* sp = slot_prob + e * CAP;
    float bj[4];
#pragma unroll
    for (int j = 0; j < 4; ++j)
      bj[j] = (ks == 0) ? bias[(size_t)e * N + n0 + wn + j * 16 + l15] : 0.f;
#pragma unroll
    for (int i = 0; i < 8; ++i) {
#pragma unroll
      for (int r = 0; r < 4; ++r) {
        int m = m0 + wm + i * 16 + quad * 4 + r;
        int tok = st[m];
        if (tok >= 0) {
          float p = sp[m];
#pragma unroll
          for (int j = 0; j < 4; ++j) {
            int n = n0 + wn + j * 16 + l15;
            float v = acc[i][j][r] + bj[j];
            atomicAdd(out + (size_t)tok * HDIM + n, p * v);
          }
        }
      }
    }
  }
}

extern "C" void kernel_launch(void* const* d_in, const int* in_sizes, int n_in,
                              void* d_out, int out_size, void* d_ws, size_t ws_size,
                              hipStream_t stream) {
  const float* x  = (const float*)d_in[0];
  const float* wr = (const float*)d_in[1];
  const float* w1 = (const float*)d_in[2];
  const float* b1 = (const float*)d_in[3];
  const float* w2 = (const float*)d_in[4];
  const float* b2 = (const float*)d_in[5];
  float* out = (float*)d_out;

  // Workspace layout (bytes). All GEMM operands K-CHUNKED: [e][k/64][row][64] bf16.
  char* ws = (char*)d_ws;
  size_t off = 0;
  __bf16* w1t = (__bf16*)(ws + off); off += (size_t)NEXP * FDIM * HDIM * 2;   // 64MB [e][H/64][F][64]
  __bf16* w2t = (__bf16*)(ws + off); off += (size_t)NEXP * HDIM * FDIM * 2;   // 64MB [e][F/64][H][64]
  __bf16* disp = (__bf16*)(ws + off); off += (size_t)NEXP * CAP * HDIM * 2;   // 40MB [e][H/64][C][64]
  __bf16* hbuf = (__bf16*)(ws + off); off += (size_t)NEXP * CAP * FDIM * 2;   // 80MB [e][F/64][C][64]
  int*   slot_token = (int*)(ws + off);  off += (size_t)NEXP * CAP * 4;
  float* slot_prob  = (float*)(ws + off); off += (size_t)NEXP * CAP * 4;
  int*   eidx  = (int*)(ws + off);  off += (size_t)T_TOK * 2 * 4;
  float* eprob = (float*)(ws + off); off += (size_t)T_TOK * 2 * 4;
  if (ws_size < off) return;  // insufficient scratch

  // Init: empty slots = -1, output accumulates via atomics
  hipMemsetAsync(slot_token, 0xFF, (size_t)NEXP * CAP * 4, stream);
  hipMemsetAsync(d_out, 0, (size_t)T_TOK * HDIM * 4, stream);

  // Weight transpose+cast into chunked layouts:
  // w1 (E,H,F) -> w1t [e][H/64][F][64]; w2 (E,F,H) -> w2t [e][F/64][H][64]
  transpose_cast_kernel<<<dim3(FDIM / 64, HDIM / 64, NEXP), 256, 0, stream>>>(w1, w1t, HDIM, FDIM);
  transpose_cast_kernel<<<dim3(HDIM / 64, FDIM / 64, NEXP), 256, 0, stream>>>(w2, w2t, FDIM, HDIM);

  // Routing
  router_kernel<<<T_TOK / 4, 256, 0, stream>>>(x, wr, eidx, eprob);
  pos_kernel<<<1, 256, 0, stream>>>(eidx, eprob, slot_token, slot_prob);
  scatter_kernel<<<NEXP * CAP / 4, 256, 0, stream>>>(x, slot_token, disp);

  // Expert FFN: 256x256 tiles, BK=64, chunked operands.
  // GEMM1 grid 8x5x16=640 (%8==0 for XCD swizzle). GEMM2 split-K=2: 4x5x32=640.
  moe_gemm_kernel<1, 1><<<dim3(FDIM / 256, CAP / 256, NEXP), 512, 0, stream>>>(
      disp, w1t, b1, hbuf, nullptr, nullptr, nullptr, CAP, FDIM, HDIM);
  moe_gemm_kernel<2, 2><<<dim3(HDIM / 256, CAP / 256, NEXP * 2), 512, 0, stream>>>(
      hbuf, w2t, b2, nullptr, slot_token, slot_prob, out, CAP, HDIM, FDIM);
}